// Round 2
// baseline (1260.617 us; speedup 1.0000x reference)
//
#include <hip/hip_runtime.h>
#include <hip/hip_bf16.h>

#define DD 32
#define TT 9
#define LL 24
#define HH 8
#define HDD 4
#define NPOS 216           // TT*LL
#define RPB_W 47           // 2*LL-1
#define ALPHA 0.9f

__device__ __forceinline__ float gelu_exact(float x) {
    return 0.5f * x * (1.0f + erff(x * 0.7071067811865476f));
}
__device__ __forceinline__ float sigmoidf(float x) { return 1.0f / (1.0f + expf(-x)); }

// ---------------- K0: A32 = ALPHA * softplus(W_causal)*(1-I) / (rowsum+1e-6) ----------------
__global__ void k0_prep(const float* __restrict__ wcausal, float* __restrict__ a32) {
    __shared__ float A[DD][DD];
    __shared__ float rs[DD];
    int tid = threadIdx.x;              // 1024 threads
    int i = tid >> 5, j = tid & 31;
    float a = (i == j) ? 0.0f : log1pf(expf(wcausal[tid]));
    A[i][j] = a;
    __syncthreads();
    if (j == 0) {
        float s = 0.0f;
        for (int k = 0; k < DD; k++) s += A[i][k];
        rs[i] = ALPHA / (s + 1e-6f);
    }
    __syncthreads();
    a32[tid] = A[i][j] * rs[i];
}

// ---------------- K1: per-batch rule pooling / intervention / Neumann -> g*delta ----------------
__global__ __launch_bounds__(256) void k1_delta(
    const float* __restrict__ x,
    const float* __restrict__ ln_g, const float* __restrict__ ln_b,
    const float* __restrict__ rp_w1, const float* __restrict__ rp_b1,
    const float* __restrict__ rp_w2, const float* __restrict__ rp_b2,
    const float* __restrict__ mask_w, const float* __restrict__ mask_b,
    const float* __restrict__ val_w1, const float* __restrict__ val_b1,
    const float* __restrict__ val_w2, const float* __restrict__ val_b2,
    const float* __restrict__ fuse_gate,
    const float* __restrict__ a32,
    float* __restrict__ delta_out)
{
    int b = blockIdx.x;
    int tid = threadIdx.x;
    __shared__ float spool[DD], ssq[DD];

    // per-channel sums over the 216 (t,l) positions; 8 threads per channel
    int c = tid >> 3, r = tid & 7;
    const float* xb = x + (size_t)b * (DD * NPOS) + (size_t)c * NPOS;
    float sum = 0.0f, ss = 0.0f;
    for (int k = r; k < NPOS; k += 8) {
        float v = xb[k];
        sum += v; ss += v * v;
    }
    for (int m = 1; m < 8; m <<= 1) {
        sum += __shfl_xor(sum, m);
        ss  += __shfl_xor(ss, m);
    }
    if (r == 0) { spool[c] = sum; ssq[c] = ss; }
    __syncthreads();

    if (tid < DD) {
        int cc = tid;
        float psum = spool[cc], psq = ssq[cc];
        float pooled = psum * (1.0f / NPOS);       // == x_obs
        // LayerNorm across channels (ddof=0)
        float tot = pooled;
        for (int m = 1; m < 32; m <<= 1) tot += __shfl_xor(tot, m);
        float mu = tot * (1.0f / DD);
        float d = pooled - mu;
        float vv = d * d;
        for (int m = 1; m < 32; m <<= 1) vv += __shfl_xor(vv, m);
        vv *= (1.0f / DD);
        float pn = d * rsqrtf(vv + 1e-5f) * ln_g[cc] + ln_b[cc];

        // rule pooling MLP: lin->gelu->lin  (out[i] = sum_j in[j]*w[i,j] + b[i])
        float acc = rp_b1[cc];
        for (int j = 0; j < DD; j++) acc += __shfl(pn, j) * rp_w1[cc * DD + j];
        float h1 = gelu_exact(acc);
        acc = rp_b2[cc];
        for (int j = 0; j < DD; j++) acc += __shfl(h1, j) * rp_w2[cc * DD + j];
        float pr = acc;                             // pooled_rule

        // mask
        float am = mask_b[cc];
        for (int j = 0; j < DD; j++) am += __shfl(pr, j) * mask_w[cc * DD + j];
        float M = sigmoidf(am);
        // value MLP
        float av = val_b1[cc];
        for (int j = 0; j < DD; j++) av += __shfl(pr, j) * val_w1[cc * DD + j];
        float g1 = gelu_exact(av);
        av = val_b2[cc];
        for (int j = 0; j < DD; j++) av += __shfl(g1, j) * val_w2[cc * DD + j];

        // scale = clip(std ddof=1, min 1e-3)
        float var1 = (psq - (float)NPOS * pooled * pooled) * (1.0f / (NPOS - 1));
        float scl = fmaxf(sqrtf(fmaxf(var1, 0.0f)), 1e-3f);

        float x_obs = pooled;
        float v32 = tanhf(av) * scl + x_obs;
        float x_do = (1.0f - M) * x_obs + M * v32;

        // Neumann series: y = x_do + y @ A32^T  (3 iterations)
        float y = x_do;
        for (int it = 0; it < 3; it++) {
            float a = x_do;
            const float* row = a32 + cc * DD;
            for (int j = 0; j < DD; j++) a += __shfl(y, j) * row[j];
            y = a;
        }
        float g = sigmoidf(fuse_gate[0]);
        delta_out[b * DD + cc] = g * (y - x_obs);
    }
}

// ---------------- K2: per (b,t) attention, writes x_att into out ----------------
__global__ __launch_bounds__(256) void k2_attn(
    const float* __restrict__ x,
    const float* __restrict__ delta,
    const float* __restrict__ q_w, const float* __restrict__ q_b,
    const float* __restrict__ k_w, const float* __restrict__ k_b,
    const float* __restrict__ v_w, const float* __restrict__ v_b,
    const float* __restrict__ m_w, const float* __restrict__ m_b,
    const float* __restrict__ w_logit, const float* __restrict__ w_ctx,
    const float* __restrict__ rpb,
    float* __restrict__ out)
{
    int blk = blockIdx.x;
    int b = blk / TT, t = blk % TT;
    int tid = threadIdx.x;

    __shared__ float fused[LL][DD + 1];          // later reused as 'cat' (head-concat PV result)
    __shared__ float qs[LL][DD + 1], ks[LL][DD + 1], vs[LL][DD + 1];
    __shared__ float wqT[DD][DD + 1], wkT[DD][DD + 1], wvT[DD][DD + 1], wmT[DD][DD + 1];
    __shared__ float bq[DD], bk[DD], bv[DD], bm[DD];
    __shared__ float wl[HH * HH], wc[HH * HH];
    __shared__ float rp[HH][RPB_W];
    __shared__ float dl[DD];
    __shared__ float lg[HH * LL * LL];           // logits / atten [h][i][j]

    // stage weights (transposed for conflict-free reads) and small vectors
    for (int idx = tid; idx < DD * DD; idx += 256) {
        int i = idx >> 5, j = idx & 31;
        wqT[j][i] = q_w[idx];
        wkT[j][i] = k_w[idx];
        wvT[j][i] = v_w[idx];
        wmT[j][i] = m_w[idx];
    }
    if (tid < DD) {
        bq[tid] = q_b[tid]; bk[tid] = k_b[tid];
        bv[tid] = v_b[tid]; bm[tid] = m_b[tid];
        dl[tid] = delta[b * DD + tid];
    }
    if (tid >= 64 && tid < 128) wl[tid - 64] = w_logit[tid - 64];
    if (tid >= 128 && tid < 192) wc[tid - 128] = w_ctx[tid - 128];
    for (int idx = tid; idx < HH * RPB_W; idx += 256)
        rp[idx / RPB_W][idx % RPB_W] = rpb[idx];
    __syncthreads();

    // fused[l][c] = x[b,c,t,l] + g*delta[c]
    for (int idx = tid; idx < DD * LL; idx += 256) {
        int c = idx / LL, l = idx % LL;
        fused[l][c] = x[(size_t)b * (DD * NPOS) + (size_t)c * NPOS + t * LL + l] + dl[c];
    }
    __syncthreads();

    // q/k/v projections + per-head L2 normalization (4-lane shuffle groups)
    int i = tid & 31, lgrp = tid >> 5;
    for (int lo = 0; lo < LL; lo += 8) {
        int l = lo + lgrp;
        float aq = bq[i], ak = bk[i], av = bv[i];
        for (int j = 0; j < DD; j++) {
            float f = fused[l][j];
            aq += f * wqT[j][i];
            ak += f * wkT[j][i];
            av += f * wvT[j][i];
        }
        float nq = aq * aq, nk = ak * ak, nv = av * av;
        nq += __shfl_xor(nq, 1); nq += __shfl_xor(nq, 2);
        nk += __shfl_xor(nk, 1); nk += __shfl_xor(nk, 2);
        nv += __shfl_xor(nv, 1); nv += __shfl_xor(nv, 2);
        qs[l][i] = aq / fmaxf(sqrtf(nq), 1e-12f);
        ks[l][i] = ak / fmaxf(sqrtf(nk), 1e-12f);
        vs[l][i] = av / fmaxf(sqrtf(nv), 1e-12f);
    }
    __syncthreads();

    // logits[h][i][j] = q.k/2 + rel_pos_bias[h, i-j+23]
    for (int idx = tid; idx < HH * LL * LL; idx += 256) {
        int h = idx / (LL * LL);
        int rem = idx - h * (LL * LL);
        int i2 = rem / LL, j2 = rem - i2 * LL;
        int hb = h * HDD;
        float acc = qs[i2][hb + 0] * ks[j2][hb + 0]
                  + qs[i2][hb + 1] * ks[j2][hb + 1]
                  + qs[i2][hb + 2] * ks[j2][hb + 2]
                  + qs[i2][hb + 3] * ks[j2][hb + 3];
        int rel = i2 - j2 + (LL - 1);
        rel = min(max(rel, 0), 2 * LL - 2);
        lg[idx] = acc * 0.5f + rp[h][rel];
    }
    __syncthreads();

    // W_logit head mix, in place over the h axis
    for (int idx = tid; idx < LL * LL; idx += 256) {
        float tmp[HH];
        for (int h = 0; h < HH; h++) tmp[h] = lg[h * (LL * LL) + idx];
        for (int Ho = 0; Ho < HH; Ho++) {
            float a = 0.0f;
            for (int h = 0; h < HH; h++) a += tmp[h] * wl[h * HH + Ho];
            lg[Ho * (LL * LL) + idx] = a;
        }
    }
    __syncthreads();

    // softmax over j per (H,i)
    if (tid < HH * LL) {
        float* row = &lg[(tid / LL) * (LL * LL) + (tid % LL) * LL];
        float mx = row[0];
        for (int j = 1; j < LL; j++) mx = fmaxf(mx, row[j]);
        float s = 0.0f;
        for (int j = 0; j < LL; j++) { float e = __expf(row[j] - mx); row[j] = e; s += e; }
        float inv = 1.0f / s;
        for (int j = 0; j < LL; j++) row[j] *= inv;
    }
    __syncthreads();

    // W_ctx head mix, in place
    for (int idx = tid; idx < LL * LL; idx += 256) {
        float tmp[HH];
        for (int h = 0; h < HH; h++) tmp[h] = lg[h * (LL * LL) + idx];
        for (int Ho = 0; Ho < HH; Ho++) {
            float a = 0.0f;
            for (int h = 0; h < HH; h++) a += tmp[h] * wc[h * HH + Ho];
            lg[Ho * (LL * LL) + idx] = a;
        }
    }
    __syncthreads();

    // PV: cat[l][h*4+d] = sum_j atten2[h,l,j] * v[j][h*4+d]   (reuse 'fused' as cat)
    for (int lo = 0; lo < LL; lo += 8) {
        int l = lo + lgrp;
        int h = i >> 2;
        const float* arow = &lg[h * (LL * LL) + l * LL];
        float acc = 0.0f;
        for (int j = 0; j < LL; j++) acc += arow[j] * vs[j][i];
        fused[l][i] = acc;
    }
    __syncthreads();

    // m_w projection and store to out[b, c, t, l]
    for (int lo = 0; lo < LL; lo += 8) {
        int l = lo + lgrp;
        float acc = bm[i];
        for (int j = 0; j < DD; j++) acc += fused[l][j] * wmT[j][i];
        out[(size_t)b * (DD * NPOS) + (size_t)i * NPOS + t * LL + l] = acc;
    }
}

// ---------------- K3: prediction branch, rewrites the t=8 plane of out ----------------
__global__ __launch_bounds__(256) void k3_pred(
    const float* __restrict__ pre_prompt,
    const float* __restrict__ conv_w, const float* __restrict__ conv_b,
    const float* __restrict__ p_w, const float* __restrict__ p_b,
    float* __restrict__ out)
{
    int b = blockIdx.x, tid = threadIdx.x;
    __shared__ float con[DD * NPOS];             // [c][t][l], t=8 plane replaced by pre_prompt
    __shared__ float xa8[DD][LL];
    __shared__ float pbuf[DD][LL];
    __shared__ float pw[LL * LL];
    __shared__ float pb[LL], cb[DD];

    for (int idx = tid; idx < DD * NPOS; idx += 256) {
        int c = idx / NPOS;
        int rem = idx - c * NPOS;
        int t = rem / LL, l = rem - t * LL;
        float v = out[(size_t)b * (DD * NPOS) + idx];
        if (t == TT - 1) {
            xa8[c][l] = v;
            con[idx] = pre_prompt[c * LL + l];
        } else {
            con[idx] = v;
        }
    }
    for (int idx = tid; idx < LL * LL; idx += 256) pw[idx] = p_w[idx];
    if (tid < LL) pb[tid] = p_b[tid];
    if (tid >= 64 && tid < 64 + DD) cb[tid - 64] = conv_b[tid - 64];
    __syncthreads();

    // conv over contexts: p[co][l] = relu(sum_{ci,t} con[ci,t,l] * conv_w[co,ci,t] + cb[co])
    // conv_w read from global: lanes share co -> broadcast loads, L1/L2 resident.
    for (int idx = tid; idx < DD * LL; idx += 256) {
        int co = idx / LL, l = idx - co * LL;
        float acc = cb[co];
        const float* w = conv_w + (size_t)co * DD * TT;
        for (int ci = 0; ci < DD; ci++) {
            const float* cc = &con[ci * NPOS + l];
            for (int t = 0; t < TT; t++)
                acc += cc[t * LL] * w[ci * TT + t];
        }
        pbuf[co][l] = fmaxf(acc, 0.0f);
    }
    __syncthreads();

    // token linear + subtraction, write t=8 plane
    for (int idx = tid; idx < DD * LL; idx += 256) {
        int c = idx / LL, l = idx - c * LL;
        float acc = pb[l];
        for (int lp = 0; lp < LL; lp++) acc += pbuf[c][lp] * pw[l * LL + lp];
        out[(size_t)b * (DD * NPOS) + c * NPOS + (TT - 1) * LL + l] = xa8[c][l] - acc;
    }
}

extern "C" void kernel_launch(void* const* d_in, const int* in_sizes, int n_in,
                              void* d_out, int out_size, void* d_ws, size_t ws_size,
                              hipStream_t stream) {
    const float* x        = (const float*)d_in[0];
    const float* ln_g     = (const float*)d_in[1];
    const float* ln_b     = (const float*)d_in[2];
    const float* rp_w1    = (const float*)d_in[3];
    const float* rp_b1    = (const float*)d_in[4];
    const float* rp_w2    = (const float*)d_in[5];
    const float* rp_b2    = (const float*)d_in[6];
    const float* W_causal = (const float*)d_in[7];
    const float* mask_w   = (const float*)d_in[8];
    const float* mask_b   = (const float*)d_in[9];
    const float* val_w1   = (const float*)d_in[10];
    const float* val_b1   = (const float*)d_in[11];
    const float* val_w2   = (const float*)d_in[12];
    const float* val_b2   = (const float*)d_in[13];
    const float* fuse_g   = (const float*)d_in[14];
    const float* q_w      = (const float*)d_in[15];
    const float* q_b      = (const float*)d_in[16];
    const float* k_w      = (const float*)d_in[17];
    const float* k_b      = (const float*)d_in[18];
    const float* v_w      = (const float*)d_in[19];
    const float* v_b      = (const float*)d_in[20];
    const float* m_w      = (const float*)d_in[21];
    const float* m_b      = (const float*)d_in[22];
    const float* W_logit  = (const float*)d_in[23];
    const float* W_ctx    = (const float*)d_in[24];
    const float* rel_pb   = (const float*)d_in[25];
    const float* pre_pr   = (const float*)d_in[26];
    const float* conv_w   = (const float*)d_in[27];
    const float* conv_b   = (const float*)d_in[28];
    const float* p_w      = (const float*)d_in[29];
    const float* p_b      = (const float*)d_in[30];
    float* out = (float*)d_out;

    int B = in_sizes[0] / (DD * NPOS);

    float* a32   = (float*)d_ws;            // 1024 floats
    float* delta = a32 + DD * DD;           // B*32 floats

    hipLaunchKernelGGL(k0_prep, dim3(1), dim3(1024), 0, stream, W_causal, a32);
    hipLaunchKernelGGL(k1_delta, dim3(B), dim3(256), 0, stream,
                       x, ln_g, ln_b, rp_w1, rp_b1, rp_w2, rp_b2,
                       mask_w, mask_b, val_w1, val_b1, val_w2, val_b2,
                       fuse_g, a32, delta);
    hipLaunchKernelGGL(k2_attn, dim3(B * TT), dim3(256), 0, stream,
                       x, delta, q_w, q_b, k_w, k_b, v_w, v_b, m_w, m_b,
                       W_logit, W_ctx, rel_pb, out);
    hipLaunchKernelGGL(k3_pred, dim3(B), dim3(256), 0, stream,
                       pre_pr, conv_w, conv_b, p_w, p_b, out);
}

// Round 3
// 1081.313 us; speedup vs baseline: 1.1658x; 1.1658x over previous
//
#include <hip/hip_runtime.h>
#include <hip/hip_bf16.h>

#define DD 32
#define TT 9
#define LL 24
#define HH 8
#define NPOS 216           // TT*LL
#define RPB_W 47           // 2*LL-1
#define ALPHA 0.9f

__device__ __forceinline__ float gelu_exact(float x) {
    return 0.5f * x * (1.0f + erff(x * 0.7071067811865476f));
}
__device__ __forceinline__ float sigmoidf_(float x) { return 1.0f / (1.0f + expf(-x)); }

// ws float layout: [0,1024) a32 ; [1024,1088) wl05 ; [1088,1472) rpm[8][48] ;
// [2048, 2048+B*32) spool (later overwritten with delta) ; then ssq (B*32)

// ---------------- K0: a32 + premixed 0.5*W_logit + premixed rel-pos bias ----------------
__global__ void k0_prep(const float* __restrict__ wcausal,
                        const float* __restrict__ w_logit,
                        const float* __restrict__ rpb,
                        float* __restrict__ ws) {
    __shared__ float A[DD][DD];
    __shared__ float rs[DD];
    int tid = threadIdx.x;              // 1024 threads
    int i = tid >> 5, j = tid & 31;
    float a = (i == j) ? 0.0f : log1pf(expf(wcausal[tid]));
    A[i][j] = a;
    __syncthreads();
    if (j == 0) {
        float s = 0.0f;
        for (int k = 0; k < DD; k++) s += A[i][k];
        rs[i] = ALPHA / (s + 1e-6f);
    }
    __syncthreads();
    ws[tid] = A[i][j] * rs[i];
    if (tid < 64) ws[1024 + tid] = 0.5f * w_logit[tid];
    if (tid < 384) {
        int H = tid / 48, r = tid % 48;
        float v = 0.0f;
        if (r < RPB_W) {
            for (int h = 0; h < HH; h++) v += w_logit[h * HH + H] * rpb[h * RPB_W + r];
        }
        ws[1088 + tid] = v;
    }
}

// ---------------- K1a: per-(b,c) sum / sum-of-squares (memory-bound) ----------------
__global__ __launch_bounds__(256) void k1a(const float* __restrict__ x,
                                           float* __restrict__ sp, float* __restrict__ sq) {
    int b = blockIdx.x, tid = threadIdx.x;
    int c = tid >> 3, r = tid & 7;
    const float4* x4 = (const float4*)(x + (size_t)b * (DD * NPOS) + (size_t)c * NPOS);
    float s = 0.0f, q = 0.0f;
    for (int k = r; k < 54; k += 8) {   // 54 float4 = 216 floats
        float4 v = x4[k];
        s += v.x + v.y + v.z + v.w;
        q += v.x * v.x + v.y * v.y + v.z * v.z + v.w * v.w;
    }
    for (int m = 1; m < 8; m <<= 1) { s += __shfl_xor(s, m); q += __shfl_xor(q, m); }
    if (r == 0) { sp[b * DD + c] = s; sq[b * DD + c] = q; }
}

// ---------------- K1b: one batch element per thread; full chain in registers ----------------
__global__ __launch_bounds__(64) void k1b(
    const float* __restrict__ ln_g, const float* __restrict__ ln_b,
    const float* __restrict__ rp_w1, const float* __restrict__ rp_b1,
    const float* __restrict__ rp_w2, const float* __restrict__ rp_b2,
    const float* __restrict__ mask_w, const float* __restrict__ mask_b,
    const float* __restrict__ val_w1, const float* __restrict__ val_b1,
    const float* __restrict__ val_w2, const float* __restrict__ val_b2,
    const float* __restrict__ fuse_gate, const float* __restrict__ ws,
    float* __restrict__ sp /* in: sums; out: g*delta */, const float* __restrict__ sq)
{
    __shared__ float W[6][1024];   // rp_w1, rp_w2, mask_w, val_w1, val_w2, a32
    __shared__ float V[7][32];     // ln_g, ln_b, rp_b1, rp_b2, mask_b, val_b1, val_b2
    int tid = threadIdx.x;
    for (int idx = tid; idx < 1024; idx += 64) {
        W[0][idx] = rp_w1[idx]; W[1][idx] = rp_w2[idx]; W[2][idx] = mask_w[idx];
        W[3][idx] = val_w1[idx]; W[4][idx] = val_w2[idx]; W[5][idx] = ws[idx];
    }
    if (tid < 32) {
        V[0][tid] = ln_g[tid]; V[1][tid] = ln_b[tid]; V[2][tid] = rp_b1[tid];
        V[3][tid] = rp_b2[tid]; V[4][tid] = mask_b[tid]; V[5][tid] = val_b1[tid];
        V[6][tid] = val_b2[tid];
    }
    __syncthreads();
    int b = blockIdx.x * 64 + tid;

    float pooled[32], scl[32];
    const float4* sp4 = (const float4*)(sp + (size_t)b * 32);
    const float4* sq4 = (const float4*)(sq + (size_t)b * 32);
    #pragma unroll
    for (int k = 0; k < 8; k++) {
        float4 sv = sp4[k], qv = sq4[k];
        float ss[4] = {sv.x, sv.y, sv.z, sv.w};
        float qq[4] = {qv.x, qv.y, qv.z, qv.w};
        #pragma unroll
        for (int m = 0; m < 4; m++) {
            int c = 4 * k + m;
            float p = ss[m] * (1.0f / NPOS);
            pooled[c] = p;
            float var1 = (qq[m] - (float)NPOS * p * p) * (1.0f / (NPOS - 1));
            scl[c] = fmaxf(sqrtf(fmaxf(var1, 0.0f)), 1e-3f);
        }
    }
    float mu = 0.0f;
    #pragma unroll
    for (int c = 0; c < 32; c++) mu += pooled[c];
    mu *= (1.0f / 32.0f);
    float vv = 0.0f;
    #pragma unroll
    for (int c = 0; c < 32; c++) { float d = pooled[c] - mu; vv += d * d; }
    vv *= (1.0f / 32.0f);
    float inv = rsqrtf(vv + 1e-5f);
    float pn[32];
    #pragma unroll
    for (int c = 0; c < 32; c++) pn[c] = (pooled[c] - mu) * inv * V[0][c] + V[1][c];

    float h1[32];
    #pragma unroll
    for (int i = 0; i < 32; i++) {
        float acc = V[2][i];
        #pragma unroll
        for (int j = 0; j < 32; j++) acc += pn[j] * W[0][i * 32 + j];
        h1[i] = gelu_exact(acc);
    }
    float pr[32];
    #pragma unroll
    for (int i = 0; i < 32; i++) {
        float acc = V[3][i];
        #pragma unroll
        for (int j = 0; j < 32; j++) acc += h1[j] * W[1][i * 32 + j];
        pr[i] = acc;
    }
    float g1[32];
    #pragma unroll
    for (int i = 0; i < 32; i++) {
        float acc = V[5][i];
        #pragma unroll
        for (int j = 0; j < 32; j++) acc += pr[j] * W[3][i * 32 + j];
        g1[i] = gelu_exact(acc);
    }
    float xd[32];
    #pragma unroll
    for (int i = 0; i < 32; i++) {
        float am = V[4][i];
        #pragma unroll
        for (int j = 0; j < 32; j++) am += pr[j] * W[2][i * 32 + j];
        float M = sigmoidf_(am);
        float av = V[6][i];
        #pragma unroll
        for (int j = 0; j < 32; j++) av += g1[j] * W[4][i * 32 + j];
        float v32 = tanhf(av) * scl[i] + pooled[i];
        xd[i] = (1.0f - M) * pooled[i] + M * v32;
    }
    float y[32];
    #pragma unroll
    for (int c = 0; c < 32; c++) y[c] = xd[c];
    for (int it = 0; it < 3; it++) {
        float ny[32];
        #pragma unroll
        for (int i = 0; i < 32; i++) {
            float acc = xd[i];
            #pragma unroll
            for (int j = 0; j < 32; j++) acc += y[j] * W[5][i * 32 + j];
            ny[i] = acc;
        }
        #pragma unroll
        for (int c = 0; c < 32; c++) y[c] = ny[c];
    }
    float g = sigmoidf_(fuse_gate[0]);
    float4* dout4 = (float4*)(sp + (size_t)b * 32);
    #pragma unroll
    for (int k = 0; k < 8; k++) {
        float4 o;
        o.x = g * (y[4 * k + 0] - pooled[4 * k + 0]);
        o.y = g * (y[4 * k + 1] - pooled[4 * k + 1]);
        o.z = g * (y[4 * k + 2] - pooled[4 * k + 2]);
        o.w = g * (y[4 * k + 3] - pooled[4 * k + 3]);
        dout4[k] = o;
    }
}

// ---------------- K2: per (b,t) attention ----------------
// LDS plan: r1 = fused/qs/ks/vs [24][36] each; r2 = union{ wq|wk|wv [32][32] , lg[8][601]+wm[32][32] }
__global__ __launch_bounds__(256) void k2_attn(
    const float* __restrict__ x,
    const float* __restrict__ ws,        // wl05 @1024, rpm @1088
    const float* __restrict__ delta,
    const float* __restrict__ q_w, const float* __restrict__ q_b,
    const float* __restrict__ k_w, const float* __restrict__ k_b,
    const float* __restrict__ v_w, const float* __restrict__ v_b,
    const float* __restrict__ m_w, const float* __restrict__ m_b,
    const float* __restrict__ w_ctx,
    float* __restrict__ out)
{
    __shared__ float r1[3456];
    __shared__ float r2[5832];
    __shared__ float msc[640];
    float* fusedf = r1;                 // [24][36]
    float* qsf = r1 + 864;
    float* ksf = r1 + 1728;
    float* vsf = r1 + 2592;
    float* wqf = r2;                    // phase A/B: [32][32] transposed (wT[j][i])
    float* wkf = r2 + 1024;
    float* wvf = r2 + 2048;
    float* lgf = r2;                    // phase C+: [8] planes, plane stride 601, row stride 25
    float* wmf = r2 + 4808;             // [32][32] transposed
    float* bqf = msc, *bkf = msc + 32, *bvf = msc + 64, *bmf = msc + 96;
    float* wl05f = msc + 128;
    float* wcf = msc + 192;
    float* rpmf = msc + 256;            // [8][48]

    int blk = blockIdx.x;
    int b = blk / TT, t = blk % TT;
    int tid = threadIdx.x;

    // ---- stage ----
    for (int idx = tid; idx < 768; idx += 256) {   // q/k/v weights, transposed
        int m = idx >> 8, r = idx & 255;
        int i = r >> 3, jq = r & 7;
        const float* src = (m == 0) ? q_w : (m == 1) ? k_w : v_w;
        float* dst = (m == 0) ? wqf : (m == 1) ? wkf : wvf;
        float4 v = ((const float4*)src)[r];
        dst[(4 * jq + 0) * 32 + i] = v.x;
        dst[(4 * jq + 1) * 32 + i] = v.y;
        dst[(4 * jq + 2) * 32 + i] = v.z;
        dst[(4 * jq + 3) * 32 + i] = v.w;
    }
    if (tid < 32) { bqf[tid] = q_b[tid]; bkf[tid] = k_b[tid]; bvf[tid] = v_b[tid]; bmf[tid] = m_b[tid]; }
    else if (tid < 96) wl05f[tid - 32] = ws[1024 + tid - 32];
    else if (tid < 160) wcf[tid - 96] = w_ctx[tid - 96];
    for (int idx = tid; idx < 384; idx += 256) rpmf[idx] = ws[1088 + idx];
    if (tid < 192) {                    // fused[l][c] = x + delta
        int c = tid / 6, k = tid % 6;
        const float4* p = (const float4*)(x + (size_t)b * (DD * NPOS) + (size_t)c * NPOS + t * LL);
        float4 v = p[k];
        float gd = delta[b * DD + c];
        int l0 = 4 * k;
        fusedf[(l0 + 0) * 36 + c] = v.x + gd;
        fusedf[(l0 + 1) * 36 + c] = v.y + gd;
        fusedf[(l0 + 2) * 36 + c] = v.z + gd;
        fusedf[(l0 + 3) * 36 + c] = v.w + gd;
    }
    __syncthreads();

    // ---- q/k/v projection: thread = (l, head q); acc quad == one head ----
    if (tid < 192) {
        int l = tid >> 3, q = tid & 7;
        float4 aq = *(const float4*)&bqf[4 * q];
        float4 ak = *(const float4*)&bkf[4 * q];
        float4 av = *(const float4*)&bvf[4 * q];
        #pragma unroll
        for (int j = 0; j < 32; j++) {
            float f = fusedf[l * 36 + j];
            float4 w0 = *(const float4*)&wqf[j * 32 + 4 * q];
            float4 w1 = *(const float4*)&wkf[j * 32 + 4 * q];
            float4 w2 = *(const float4*)&wvf[j * 32 + 4 * q];
            aq.x += f * w0.x; aq.y += f * w0.y; aq.z += f * w0.z; aq.w += f * w0.w;
            ak.x += f * w1.x; ak.y += f * w1.y; ak.z += f * w1.z; ak.w += f * w1.w;
            av.x += f * w2.x; av.y += f * w2.y; av.z += f * w2.z; av.w += f * w2.w;
        }
        float nq = 1.0f / fmaxf(sqrtf(aq.x*aq.x + aq.y*aq.y + aq.z*aq.z + aq.w*aq.w), 1e-12f);
        float nk = 1.0f / fmaxf(sqrtf(ak.x*ak.x + ak.y*ak.y + ak.z*ak.z + ak.w*ak.w), 1e-12f);
        float nv = 1.0f / fmaxf(sqrtf(av.x*av.x + av.y*av.y + av.z*av.z + av.w*av.w), 1e-12f);
        aq.x *= nq; aq.y *= nq; aq.z *= nq; aq.w *= nq;
        ak.x *= nk; ak.y *= nk; ak.z *= nk; ak.w *= nk;
        av.x *= nv; av.y *= nv; av.z *= nv; av.w *= nv;
        *(float4*)&qsf[l * 36 + 4 * q] = aq;
        *(float4*)&ksf[l * 36 + 4 * q] = ak;
        *(float4*)&vsf[l * 36 + 4 * q] = av;
    }
    __syncthreads();

    // ---- stage wm (into r2 tail, wq/wk/wv now dead) + raw logits ----
    {
        int idx = tid;   // 256 float4 = whole m_w
        int i = idx >> 3, jq = idx & 7;
        float4 v = ((const float4*)m_w)[idx];
        wmf[(4 * jq + 0) * 32 + i] = v.x;
        wmf[(4 * jq + 1) * 32 + i] = v.y;
        wmf[(4 * jq + 2) * 32 + i] = v.z;
        wmf[(4 * jq + 3) * 32 + i] = v.w;
    }
    if (tid < 192) {                    // thread = (h, i2): one logit row
        int h = tid / 24, i2 = tid % 24;
        float4 q4 = *(const float4*)&qsf[i2 * 36 + 4 * h];
        float row[24];
        #pragma unroll
        for (int j = 0; j < 24; j++) {
            float4 k4 = *(const float4*)&ksf[j * 36 + 4 * h];
            row[j] = q4.x * k4.x + q4.y * k4.y + q4.z * k4.z + q4.w * k4.w;
        }
        #pragma unroll
        for (int j = 0; j < 24; j++) lgf[h * 601 + i2 * 25 + j] = row[j];
    }
    __syncthreads();

    // ---- W_logit mix (0.5 folded) + premixed rel-pos bias ----
    for (int ij = tid; ij < 576; ij += 256) {
        int i = ij / 24, j = ij - i * 24;
        int off = i * 25 + j;
        int rel = i - j + (LL - 1);
        float tmp[8];
        #pragma unroll
        for (int h = 0; h < 8; h++) tmp[h] = lgf[h * 601 + off];
        #pragma unroll
        for (int H = 0; H < 8; H++) {
            float a = rpmf[H * 48 + rel];
            #pragma unroll
            for (int h = 0; h < 8; h++) a += tmp[h] * wl05f[h * 8 + H];
            lgf[H * 601 + off] = a;
        }
    }
    __syncthreads();

    // ---- softmax over j ----
    if (tid < 192) {
        int H = tid / 24, i = tid % 24;
        float* rp = &lgf[H * 601 + i * 25];
        float mx = -1e30f;
        #pragma unroll
        for (int j = 0; j < 24; j++) mx = fmaxf(mx, rp[j]);
        float s = 0.0f;
        #pragma unroll
        for (int j = 0; j < 24; j++) { float e = __expf(rp[j] - mx); rp[j] = e; s += e; }
        float inv = 1.0f / s;
        #pragma unroll
        for (int j = 0; j < 24; j++) rp[j] *= inv;
    }
    __syncthreads();

    // ---- W_ctx mix ----
    for (int ij = tid; ij < 576; ij += 256) {
        int i = ij / 24, j = ij - i * 24;
        int off = i * 25 + j;
        float tmp[8];
        #pragma unroll
        for (int h = 0; h < 8; h++) tmp[h] = lgf[h * 601 + off];
        #pragma unroll
        for (int H = 0; H < 8; H++) {
            float a = 0.0f;
            #pragma unroll
            for (int h = 0; h < 8; h++) a += tmp[h] * wcf[h * 8 + H];
            lgf[H * 601 + off] = a;
        }
    }
    __syncthreads();

    // ---- PV: thread = (l, head q); cat written into fused region ----
    if (tid < 192) {
        int l = tid >> 3, q = tid & 7;
        float4 acc = {0.0f, 0.0f, 0.0f, 0.0f};
        #pragma unroll
        for (int j = 0; j < 24; j++) {
            float a = lgf[q * 601 + l * 25 + j];
            float4 v4 = *(const float4*)&vsf[j * 36 + 4 * q];
            acc.x += a * v4.x; acc.y += a * v4.y; acc.z += a * v4.z; acc.w += a * v4.w;
        }
        *(float4*)&fusedf[l * 36 + 4 * q] = acc;
    }
    __syncthreads();

    // ---- m_w projection -> res[c][l] (stride 25, reuses qs region) ----
    if (tid < 192) {
        int l = tid >> 3, q = tid & 7;
        float4 acc = *(const float4*)&bmf[4 * q];
        #pragma unroll
        for (int c = 0; c < 32; c++) {
            float f = fusedf[l * 36 + c];
            float4 w4 = *(const float4*)&wmf[c * 32 + 4 * q];
            acc.x += f * w4.x; acc.y += f * w4.y; acc.z += f * w4.z; acc.w += f * w4.w;
        }
        float* resf = qsf;
        resf[(4 * q + 0) * 25 + l] = acc.x;
        resf[(4 * q + 1) * 25 + l] = acc.y;
        resf[(4 * q + 2) * 25 + l] = acc.z;
        resf[(4 * q + 3) * 25 + l] = acc.w;
    }
    __syncthreads();

    // ---- coalesced global write ----
    if (tid < 192) {
        const float* resf = qsf;
        int c = tid / 6, k = tid - c * 6;
        float4 v;
        v.x = resf[c * 25 + 4 * k + 0];
        v.y = resf[c * 25 + 4 * k + 1];
        v.z = resf[c * 25 + 4 * k + 2];
        v.w = resf[c * 25 + 4 * k + 3];
        float4* o4 = (float4*)(out + (size_t)b * (DD * NPOS) + (size_t)c * NPOS + t * LL);
        o4[k] = v;
    }
}

// ---------------- K3: prediction branch ----------------
__global__ __launch_bounds__(256) void k3_pred(
    const float* __restrict__ pre_prompt,
    const float* __restrict__ conv_w, const float* __restrict__ conv_b,
    const float* __restrict__ p_w, const float* __restrict__ p_b,
    float* __restrict__ out)
{
    __shared__ float conf[DD * NPOS];            // 6912 floats
    __shared__ __hip_bfloat16 cwh[DD * 292];     // conv_w, per-co stride 292 (288 used)
    __shared__ float pbuff[DD * 25];             // [co][l] stride 25
    __shared__ __hip_bfloat16 pwh[576];
    __shared__ float pbv[24], cbv[32];
    int b = blockIdx.x, tid = threadIdx.x;

    const float4* o4 = (const float4*)(out + (size_t)b * (DD * NPOS));
    for (int idx = tid; idx < 1728; idx += 256) {
        int flat = idx * 4;
        int t = (flat % NPOS) / LL;              // uniform within the float4
        float4 v;
        if (t < 8) {
            v = o4[idx];
        } else {
            int c = flat / NPOS, l = flat % LL;  // 192 % 24 == 0
            v = ((const float4*)pre_prompt)[(c * LL + l) >> 2];
        }
        conf[flat + 0] = v.x; conf[flat + 1] = v.y; conf[flat + 2] = v.z; conf[flat + 3] = v.w;
    }
    for (int idx = tid; idx < 2304; idx += 256) {
        float4 v = ((const float4*)conv_w)[idx];
        int flat = idx * 4;
        float vv[4] = {v.x, v.y, v.z, v.w};
        #pragma unroll
        for (int e = 0; e < 4; e++) {
            int f = flat + e;
            int co = f / 288, r = f - co * 288;
            cwh[co * 292 + r] = __float2bfloat16(vv[e]);
        }
    }
    for (int idx = tid; idx < 144; idx += 256) {
        float4 v = ((const float4*)p_w)[idx];
        pwh[idx * 4 + 0] = __float2bfloat16(v.x);
        pwh[idx * 4 + 1] = __float2bfloat16(v.y);
        pwh[idx * 4 + 2] = __float2bfloat16(v.z);
        pwh[idx * 4 + 3] = __float2bfloat16(v.w);
    }
    if (tid < 24) pbv[tid] = p_b[tid];
    if (tid >= 32 && tid < 64) cbv[tid - 32] = conv_b[tid - 32];
    __syncthreads();

    // conv over contexts: thread = (co, l-quad)
    if (tid < 192) {
        int co = tid / 6, ql = tid - co * 6;
        float cb = cbv[co];
        float4 acc = {cb, cb, cb, cb};
        for (int ci = 0; ci < 32; ci++) {
            #pragma unroll
            for (int tt = 0; tt < 9; tt++) {
                float w = __bfloat162float(cwh[co * 292 + ci * 9 + tt]);
                float4 v = *(const float4*)&conf[ci * NPOS + tt * LL + ql * 4];
                acc.x += w * v.x; acc.y += w * v.y; acc.z += w * v.z; acc.w += w * v.w;
            }
        }
        pbuff[co * 25 + 4 * ql + 0] = fmaxf(acc.x, 0.0f);
        pbuff[co * 25 + 4 * ql + 1] = fmaxf(acc.y, 0.0f);
        pbuff[co * 25 + 4 * ql + 2] = fmaxf(acc.z, 0.0f);
        pbuff[co * 25 + 4 * ql + 3] = fmaxf(acc.w, 0.0f);
    }
    __syncthreads();

    // token linear + subtraction into the t=8 plane
    if (tid < 192) {
        int c = tid / 6, ql = tid - c * 6;
        float4 acc = {pbv[4 * ql + 0], pbv[4 * ql + 1], pbv[4 * ql + 2], pbv[4 * ql + 3]};
        #pragma unroll
        for (int lp = 0; lp < 24; lp++) {
            float pv = pbuff[c * 25 + lp];
            acc.x += pv * __bfloat162float(pwh[(4 * ql + 0) * 24 + lp]);
            acc.y += pv * __bfloat162float(pwh[(4 * ql + 1) * 24 + lp]);
            acc.z += pv * __bfloat162float(pwh[(4 * ql + 2) * 24 + lp]);
            acc.w += pv * __bfloat162float(pwh[(4 * ql + 3) * 24 + lp]);
        }
        float4* op = (float4*)(out + (size_t)b * (DD * NPOS) + (size_t)c * NPOS + 8 * LL);
        float4 xa = op[ql];
        float4 r;
        r.x = xa.x - acc.x; r.y = xa.y - acc.y; r.z = xa.z - acc.z; r.w = xa.w - acc.w;
        op[ql] = r;
    }
}

extern "C" void kernel_launch(void* const* d_in, const int* in_sizes, int n_in,
                              void* d_out, int out_size, void* d_ws, size_t ws_size,
                              hipStream_t stream) {
    const float* x        = (const float*)d_in[0];
    const float* ln_g     = (const float*)d_in[1];
    const float* ln_b     = (const float*)d_in[2];
    const float* rp_w1    = (const float*)d_in[3];
    const float* rp_b1    = (const float*)d_in[4];
    const float* rp_w2    = (const float*)d_in[5];
    const float* rp_b2    = (const float*)d_in[6];
    const float* W_causal = (const float*)d_in[7];
    const float* mask_w   = (const float*)d_in[8];
    const float* mask_b   = (const float*)d_in[9];
    const float* val_w1   = (const float*)d_in[10];
    const float* val_b1   = (const float*)d_in[11];
    const float* val_w2   = (const float*)d_in[12];
    const float* val_b2   = (const float*)d_in[13];
    const float* fuse_g   = (const float*)d_in[14];
    const float* q_w      = (const float*)d_in[15];
    const float* q_b      = (const float*)d_in[16];
    const float* k_w      = (const float*)d_in[17];
    const float* k_b      = (const float*)d_in[18];
    const float* v_w      = (const float*)d_in[19];
    const float* v_b      = (const float*)d_in[20];
    const float* m_w      = (const float*)d_in[21];
    const float* m_b      = (const float*)d_in[22];
    const float* W_logit  = (const float*)d_in[23];
    const float* W_ctx    = (const float*)d_in[24];
    const float* rel_pb   = (const float*)d_in[25];
    const float* pre_pr   = (const float*)d_in[26];
    const float* conv_w   = (const float*)d_in[27];
    const float* conv_b   = (const float*)d_in[28];
    const float* p_w      = (const float*)d_in[29];
    const float* p_b      = (const float*)d_in[30];
    float* out = (float*)d_out;

    int B = in_sizes[0] / (DD * NPOS);

    float* ws = (float*)d_ws;
    float* sp = ws + 2048;            // B*32 sums, then overwritten with g*delta
    float* sq = sp + (size_t)B * 32;  // B*32 sum-of-squares

    hipLaunchKernelGGL(k0_prep, dim3(1), dim3(1024), 0, stream, W_causal, W_logit, rel_pb, ws);
    hipLaunchKernelGGL(k1a, dim3(B), dim3(256), 0, stream, x, sp, sq);
    hipLaunchKernelGGL(k1b, dim3(B / 64), dim3(64), 0, stream,
                       ln_g, ln_b, rp_w1, rp_b1, rp_w2, rp_b2,
                       mask_w, mask_b, val_w1, val_b1, val_w2, val_b2,
                       fuse_g, ws, sp, sq);
    hipLaunchKernelGGL(k2_attn, dim3(B * TT), dim3(256), 0, stream,
                       x, ws, sp, q_w, q_b, k_w, k_b, v_w, v_b, m_w, m_b,
                       W_ctx, out);
    hipLaunchKernelGGL(k3_pred, dim3(B), dim3(256), 0, stream,
                       pre_pr, conv_w, conv_b, p_w, p_b, out);
}